// Round 6
// baseline (84.132 us; speedup 1.0000x reference)
//
#include <hip/hip_runtime.h>
#include <cstdint>

#pragma clang fp contract(off)

#define NB      32
#define NC      18
#define NA      8400
#define NCH     (4 + NC)
#define NTASK   (NB * NC)      // 576
#define TOPK    300
#define TARGET  316        // fast path needs pcnt >= TOPK; 316 keeps margin
#define NBINS   2048
#define CAP     1024
#define CONF    0.25f
#define IOU_T   0.45f
#define NT      512
#define NW      (NT / 64)
// Prefilter: N(0,1) logits, top-316 cutoff ~1.75 +- 0.1; count(x>1.4) in [553,803] (5-sigma).
// Fast path requires TARGET <= pcnt <= CAP, else exact fallback.
#define PREF_X  1.4f
// sigmoid(x) > 0.25  <=>  x > -ln(3). Outside [XLO,XHI] analytic compare is exact.
#define XHI     (-1.0984f)
#define XLO     (-1.0988f)

// Fast-path binning is on SIGMOID bits (positive floats: raw bits monotone).
// x>1.4 => sv > 0.80218 => bits >= 0x3F4D6049 > SV_KBASE. sv<=1.0 => bin<=1632<NBINS.
#define SV_KBASE 0x3F4D0000u
#define SV_SHIFT 11
// Fallback binning: conf_pass x-mono-keys start ~0x40735C26.
#define FB_KBASE   0x40000000u
#define FB_SHIFT   21

// Exact div-free IoU compare: RN_f32(inter/D) > 0.45f  <=>  inter > M45*D.
// M45 = fp32(0.45) + 2^-26 (25-bit mantissa, exact in f64; x 24-bit D -> exact
// 49-bit product). Tie rounds-to-even back to 0.45f => not >, matching. Bit-exact.
#define M45 (30198989.0 / 67108864.0)

typedef unsigned long long ull;

__device__ __forceinline__ float sigmoidf(float x) {
    return 1.0f / (1.0f + expf(-x));
}
__device__ __forceinline__ unsigned int mono_key(unsigned int bits) {
    return (bits & 0x80000000u) ? ~bits : (bits | 0x80000000u);
}
__device__ __forceinline__ bool conf_pass(float x) {
    if (x >= XHI) return true;
    if (x <= XLO) return false;
    return sigmoidf(x) > CONF;   // rare exact band (~1 element per task)
}
__device__ __forceinline__ unsigned int make_key(float x) {
    return conf_pass(x) ? mono_key(__float_as_uint(x)) : 0u;
}
__device__ __forceinline__ ull readlane64(ull v, int i) {
    unsigned lo = (unsigned)__builtin_amdgcn_readlane((int)(unsigned)(v & 0xFFFFFFFFull), i);
    unsigned hi = (unsigned)__builtin_amdgcn_readlane((int)(unsigned)(v >> 32), i);
    return ((ull)hi << 32) | (ull)lo;
}

// Suffix-find over hist: T1 s.t. count(bins > T1) < target <= count(bins >= T1).
// (fallback path only)
__device__ __forceinline__ void suffix_find(unsigned int* hist, unsigned int* wtot,
                                            int target, int tid, int* s_T1) {
    const int base = tid * (NBINS / NT);
    unsigned int v = 0;
#pragma unroll
    for (int k = 0; k < NBINS / NT; ++k) v += hist[base + k];
    const int lane = tid & 63;
    unsigned int s = v;
#pragma unroll
    for (int d = 1; d < 64; d <<= 1) {
        unsigned int o = __shfl_down(s, d, 64);
        if (lane + d < 64) s += o;
    }
    if (lane == 0) wtot[tid >> 6] = s;
    __syncthreads();
    unsigned int above_waves = 0;
    for (int wv = (tid >> 6) + 1; wv < NW; ++wv) above_waves += wtot[wv];
    unsigned int acc = (s - v) + above_waves;
    for (int bin = base + (NBINS / NT) - 1; bin >= base; --bin) {
        unsigned int cnt = hist[bin];
        if (acc < (unsigned int)target && acc + cnt >= (unsigned int)target) *s_T1 = bin;
        acc += cnt;
    }
    __syncthreads();
}

// Pool layout: [0,8192) hist (suffix-scanned IN PLACE -> S; cand2 in fallback;
// -> sSup) ; [8192,16384) cand (-> sorted). All reuses are barrier-separated.
#define OFF_CAND   8192
#define POOL1_BYTES 16384

// PIN: keep loaded mask words in VGPRs across the serial scan (compiler
// otherwise rematerializes the loads inside the scan loop).
#define PIN64(x) asm volatile("" : "+v"(x))

// ============ Fused: select -> counting-sort rank -> compacted NMS -> output.
// One block per task; all intermediates in LDS.
// (1) Exact counting sort on sigmoid-bit keys; suffix-scan runs IN PLACE over
//     hist (count recovered as S[bin-1]-S[bin], S[-1]:=pcnt) -> no S array.
// (2) Scattered box-gather loads issue BEFORE the suffix-scan so their HBM
//     latency hides under the scan (stage reads of cand complete pre-barrier,
//     so the sorted-overlays-cand scatter stays race-free).
// (3) Zero-area rows (~75%) provably have inter==0.0f vs all boxes -> NMS in
//     compacted active space; mask build writes all 5 words per active row
//     (0 outside [w0,wlast]) so only tail rows [nAct,ceil64) need zeroing,
//     fused into the mask phase (disjoint addresses, no extra barrier).
__global__ __launch_bounds__(NT, 4) void k_fused(const float* __restrict__ in,
                                                 float* __restrict__ out) {
    __shared__ __align__(16) unsigned char pool[POOL1_BYTES];
    __shared__ __align__(16) float4 sBox[TOPK];
    __shared__ float sVal[TOPK];
    __shared__ float sAr[TOPK];
    __shared__ unsigned short slotArr[CAP];   // within-bin arrival slot
    __shared__ unsigned int wtot[NW];
    __shared__ unsigned short actIdx[TOPK];   // compacted pos -> row
    __shared__ unsigned short sPos[TOPK];     // row -> compacted pos
    __shared__ ull s_remC[5];                 // compacted suppressed bits
    __shared__ unsigned int s_cnt, s_cnt2, s_nAct;
    __shared__ int s_T1;

    unsigned int* hist = (unsigned int*)pool;   // -> S (in-place suffix counts)
    ull* cand   = (ull*)(pool + OFF_CAND);
    ull* sorted = (ull*)(pool + OFF_CAND);  // overlays cand, barrier-separated
    ull* cand2  = (ull*)pool;               // fallback only
    ull* sSup   = (ull*)pool;               // valid after rank barrier

    const int tid = threadIdx.x;
    const int lane = tid & 63;
    const int wave = tid >> 6;
    const ull ltm = (1ull << lane) - 1ull;
    const int t = blockIdx.x;
    // XCD swizzle: image b -> XCD b%8 (18 class-tasks of an image share box rows in L2)
    const int b = (t & 7) + 8 * ((t >> 3) & 3);
    const int c = t >> 5;
    const float* cls = in + (size_t)b * NCH * NA + (size_t)(4 + c) * NA;
    const float* box = in + (size_t)b * NCH * NA;

    // issue first two P1 loads BEFORE LDS init (latency hides under zeroing)
    const float4* cls4 = (const float4*)cls;
    float4 v  = cls4[tid];              // tid < 512 <= 2100: valid
    float4 vn = cls4[tid + NT];         // tid+512 <= 1023 < 2100: valid

    for (int i = tid; i < NBINS; i += NT) hist[i] = 0;
    if (tid == 0) { s_cnt = 0; s_cnt2 = 0; s_T1 = -1; }
    __syncthreads();

    // P1: prefilter x>1.4, wave-aggregated compaction; sv computed here; sv-bin
    // histogram (atomic return = slot). 2-deep rolling prefetch.
    for (int q = tid; q < NA / 4; q += NT) {
        const int qpp = q + 2 * NT;
        float4 vf;
        const bool havef = qpp < NA / 4;
        if (havef) vf = cls4[qpp];

        const unsigned int i0 = (unsigned int)q * 4u;
        float xs[4] = {v.x, v.y, v.z, v.w};
        ull m[4];
        unsigned int cnt = 0;
#pragma unroll
        for (int u = 0; u < 4; ++u) {
            m[u] = __ballot(xs[u] > PREF_X);
            cnt += (unsigned int)__popcll(m[u]);
        }
        if (cnt) {
            unsigned int base = 0;
            if (lane == 0) base = atomicAdd(&s_cnt, cnt);
            base = (unsigned int)__builtin_amdgcn_readfirstlane((int)base);
            unsigned int pre = 0;
#pragma unroll
            for (int u = 0; u < 4; ++u) {
                if (xs[u] > PREF_X) {
                    float sv = sigmoidf(xs[u]);
                    unsigned int svb = __float_as_uint(sv);
                    unsigned int bin = min((svb - SV_KBASE) >> SV_SHIFT,
                                           (unsigned)(NBINS - 1));
                    unsigned int slot = atomicAdd(&hist[bin], 1u);
                    unsigned int p = base + pre + (unsigned int)__popcll(m[u] & ltm);
                    if (p < CAP) {
                        cand[p] = ((ull)svb << 32) | (ull)(~(i0 + u));
                        slotArr[p] = (unsigned short)slot;
                    }
                }
                pre += (unsigned int)__popcll(m[u]);
            }
        }
        v = vn; vn = vf;
    }
    __syncthreads();

    const int pcnt = (int)s_cnt;
    int numSel;
    if (pcnt >= TARGET && pcnt <= CAP) {
        // ================= fast path: exact counting-sort rank =================
        numSel = TOPK;    // pcnt >= 316 > 300

        // stage A: read my <=2 candidates and ISSUE scattered box gathers NOW --
        // their ~600-900cy latency hides under the suffix-scan below. All cand
        // reads complete before the scan's barriers, so the later scatter into
        // sorted (which overlays cand) is race-free.
        ull k0 = 0, k1 = 0;
        unsigned int slot0 = 0, slot1 = 0;
        const bool a0 = tid < pcnt, a1 = tid + NT < pcnt;
        float cx0 = 0.f, cy0 = 0.f, w0 = 0.f, h0 = 0.f;
        float cx1 = 0.f, cy1 = 0.f, w1 = 0.f, h1 = 0.f;
        if (a0) {
            k0 = cand[tid];
            slot0 = (unsigned int)slotArr[tid];
            unsigned int i = ~(unsigned int)(k0 & 0xFFFFFFFFull);
            cx0 = box[i]; cy0 = box[NA + i]; w0 = box[2 * NA + i]; h0 = box[3 * NA + i];
        }
        if (a1) {
            k1 = cand[tid + NT];
            slot1 = (unsigned int)slotArr[tid + NT];
            unsigned int i = ~(unsigned int)(k1 & 0xFFFFFFFFull);
            cx1 = box[i]; cy1 = box[NA + i]; w1 = box[2 * NA + i]; h1 = box[3 * NA + i];
        }

        // in-place suffix-scan: hist[bin] := S[bin] = # keys in bins > bin.
        // Each thread touches only its own 4 bins until the final barrier.
        {
            const int basebin = tid * (NBINS / NT);
            unsigned int cs[NBINS / NT];
            unsigned int vsum = 0;
#pragma unroll
            for (int k = 0; k < NBINS / NT; ++k) { cs[k] = hist[basebin + k]; vsum += cs[k]; }
            unsigned int s = vsum;
#pragma unroll
            for (int d = 1; d < 64; d <<= 1) {
                unsigned int o = __shfl_down(s, d, 64);
                if (lane + d < 64) s += o;
            }
            if (lane == 0) wtot[wave] = s;
            __syncthreads();
            unsigned int above = 0;
            for (int w2 = wave + 1; w2 < NW; ++w2) above += wtot[w2];
            unsigned int acc = (s - vsum) + above;
#pragma unroll
            for (int k = NBINS / NT - 1; k >= 0; --k) { hist[basebin + k] = acc; acc += cs[k]; }
        }
        __syncthreads();

        // compute positions from S (=hist), scatter into sorted
        unsigned int pos0 = 0, pos1 = 0, g0 = 0, g1 = 0, c0 = 0, c1 = 0;
        if (a0) {
            unsigned int svb = (unsigned int)(k0 >> 32);
            unsigned int bin = min((svb - SV_KBASE) >> SV_SHIFT, (unsigned)(NBINS - 1));
            g0 = hist[bin];
            c0 = (bin ? hist[bin - 1] : (unsigned int)pcnt) - g0;
            pos0 = g0 + slot0;
            sorted[pos0] = k0;
        }
        if (a1) {
            unsigned int svb = (unsigned int)(k1 >> 32);
            unsigned int bin = min((svb - SV_KBASE) >> SV_SHIFT, (unsigned)(NBINS - 1));
            g1 = hist[bin];
            c1 = (bin ? hist[bin - 1] : (unsigned int)pcnt) - g1;
            pos1 = g1 + slot1;
            sorted[pos1] = k1;
        }
        __syncthreads();

        // final rank = S[bin] + #(bin-mates with greater key); gather-write
        if (a0) {
            int rank = (int)g0;
            for (unsigned int j = g0; j < g0 + c0; ++j) rank += (sorted[j] > k0) ? 1 : 0;
            if (rank < TOPK) {
                float hw = w0 * 0.5f, hh = h0 * 0.5f;
                float x1 = cx0 - hw, y1 = cy0 - hh, x2 = cx0 + hw, y2 = cy0 + hh;
                sBox[rank] = float4{x1, y1, x2, y2};
                sVal[rank] = __uint_as_float((unsigned int)(k0 >> 32));
                sAr[rank] = fmaxf(x2 - x1, 0.f) * fmaxf(y2 - y1, 0.f);
            }
        }
        if (a1) {
            int rank = (int)g1;
            for (unsigned int j = g1; j < g1 + c1; ++j) rank += (sorted[j] > k1) ? 1 : 0;
            if (rank < TOPK) {
                float hw = w1 * 0.5f, hh = h1 * 0.5f;
                float x1 = cx1 - hw, y1 = cy1 - hh, x2 = cx1 + hw, y2 = cy1 + hh;
                sBox[rank] = float4{x1, y1, x2, y2};
                sVal[rank] = __uint_as_float((unsigned int)(k1 >> 32));
                sAr[rank] = fmaxf(x2 - x1, 0.f) * fmaxf(y2 - y1, 0.f);
            }
        }
        __syncthreads();      // sorted dead; pool -> sSup
    } else {
        // ---- exact fallback (rare): re-zero hist, full conf_pass histogram,
        // threshold, then O(F^2) rank-by-counting (verbatim from R4). ----
        __syncthreads();
        for (int i = tid; i < NBINS; i += NT) hist[i] = 0;
        __syncthreads();
        {
            for (int q = tid; q < NA / 4; q += NT) {
                float4 vq = cls4[q];
                unsigned int kx = make_key(vq.x), ky = make_key(vq.y);
                unsigned int kz = make_key(vq.z), kw = make_key(vq.w);
                if (kx) atomicAdd(&hist[min((kx - FB_KBASE) >> FB_SHIFT, (unsigned)(NBINS - 1))], 1u);
                if (ky) atomicAdd(&hist[min((ky - FB_KBASE) >> FB_SHIFT, (unsigned)(NBINS - 1))], 1u);
                if (kz) atomicAdd(&hist[min((kz - FB_KBASE) >> FB_SHIFT, (unsigned)(NBINS - 1))], 1u);
                if (kw) atomicAdd(&hist[min((kw - FB_KBASE) >> FB_SHIFT, (unsigned)(NBINS - 1))], 1u);
            }
        }
        __syncthreads();
        suffix_find(hist, wtot, TARGET, tid, &s_T1);
        {
            const ull thr = (s_T1 < 0) ? 0ull
                : ((ull)FB_KBASE + ((ull)(unsigned int)s_T1 << FB_SHIFT));
            for (int q = tid; q < NA / 4; q += NT) {
                float4 vq = cls4[q];
                const unsigned int i0 = (unsigned int)q * 4u;
                float xs[4] = {vq.x, vq.y, vq.z, vq.w};
#pragma unroll
                for (int u = 0; u < 4; ++u) {
                    unsigned int d = make_key(xs[u]);
                    if (d && (ull)d >= thr) {
                        unsigned int p = atomicAdd(&s_cnt2, 1u);
                        if (p < CAP) {
                            float sv = sigmoidf(xs[u]);
                            cand2[p] = ((ull)__float_as_uint(sv) << 32) | (ull)(~(i0 + u));
                        }
                    }
                }
            }
        }
        __syncthreads();
        const int F = min((int)s_cnt2, CAP);
        numSel = min(F, TOPK);
        for (int e = tid; e < F; e += NT) {
            ull k = cand2[e];
            unsigned int i = ~(unsigned int)(k & 0xFFFFFFFFull);
            float cx = box[i];
            float cy = box[NA + i];
            float w  = box[2 * NA + i];
            float h  = box[3 * NA + i];
            int rank = 0;
            int o = 0;
#pragma unroll 2
            for (; o + 4 <= F; o += 4) {
                ulonglong2 p0 = *(const ulonglong2*)&cand2[o];
                ulonglong2 p1 = *(const ulonglong2*)&cand2[o + 2];
                rank += (p0.x > k) + (p0.y > k) + (p1.x > k) + (p1.y > k);
            }
            for (; o < F; ++o) rank += (cand2[o] > k) ? 1 : 0;
            if (rank < TOPK) {
                float hw = w * 0.5f, hh = h * 0.5f;
                float x1 = cx - hw, y1 = cy - hh, x2 = cx + hw, y2 = cy + hh;
                sBox[rank] = float4{x1, y1, x2, y2};
                sVal[rank] = __uint_as_float((unsigned int)(k >> 32));
                sAr[rank] = fmaxf(x2 - x1, 0.f) * fmaxf(y2 - y1, 0.f);
            }
        }
        __syncthreads();      // cand2 dead; pool -> sSup
    }

    // ---- order-preserving compaction of active rows ----
    {
        int r = tid;
        bool act = (r < TOPK) && (r < numSel) && (sAr[r] > 0.0f);
        ull mb = __ballot(act);
        if (lane == 0) wtot[wave] = (unsigned int)__popcll(mb);
        __syncthreads();
        unsigned int basew = 0;
        for (int w2 = 0; w2 < wave; ++w2) basew += wtot[w2];
        if (tid == 0) {
            unsigned int tot = 0;
            for (int w2 = 0; w2 < NW; ++w2) tot += wtot[w2];
            s_nAct = tot;
        }
        if (act) {
            unsigned int p = basew + (unsigned int)__popcll(mb & ltm);
            actIdx[p] = (unsigned short)r;
            sPos[r] = (unsigned short)p;
        }
    }
    __syncthreads();
    const int nAct = (int)s_nAct;

    // ---- suppression-mask build in COMPACTED space: every active row writes
    // all 5 words (0 outside [w0,wlast]); tail rows [nAct, ceil64(nAct)) zeroed
    // in the same phase (disjoint addresses -> no barrier needed between). ----
    {
        float4 cb[5];
        float ca[5];
#pragma unroll
        for (int w = 0; w < 5; ++w) {
            int jc = (w << 6) + lane;
            bool vv = jc < nAct;
            int j = vv ? (int)actIdx[jc] : 0;
            cb[w] = vv ? sBox[j] : float4{0.f, 0.f, 0.f, 0.f};
            ca[w] = vv ? sAr[j] : 0.f;
        }
        const int wlast = (nAct > 0) ? ((nAct - 1) >> 6) : -1;
        for (int p = wave; p < nAct; p += NW) {
            int r = actIdx[p];
            float4 bi = sBox[r];
            float ai = sAr[r];
            const int w0 = p >> 6;
#pragma unroll
            for (int w = 0; w < 5; ++w) {
                ull bal = 0ull;
                if (w >= w0 && w <= wlast) {   // uniform branch
                    const int jc = (w << 6) + lane;
                    bool supb = false;
                    if (jc < nAct && jc > p) {
                        float xx1 = fmaxf(bi.x, cb[w].x);
                        float yy1 = fmaxf(bi.y, cb[w].y);
                        float xx2 = fminf(bi.z, cb[w].z);
                        float yy2 = fminf(bi.w, cb[w].w);
                        float iw = fmaxf(xx2 - xx1, 0.0f);
                        float ih = fmaxf(yy2 - yy1, 0.0f);
                        float inter = iw * ih;
                        float un = ai + ca[w] - inter;
                        float D = fmaxf(un, 1e-9f);
                        supb = (double)inter > M45 * (double)D;  // == RN(inter/D) > 0.45f
                    }
                    bal = __ballot(supb);
                }
                if (lane == 0) sSup[p * 5 + w] = bal;
            }
        }
        // tail zero: rows [nAct, ceil64(nAct)) so scan's full 64-lane group
        // reads see zeros past nAct. Rows >= ceil64 are never read.
        const int zend = min((nAct + 63) & ~63, TOPK);
        for (int i = nAct * 5 + tid; i < zend * 5; i += NT) sSup[i] = 0ull;
    }
    __syncthreads();

    // ---- greedy scan over compacted rows (wave 0). nz-skip over zero rows. ----
    if (wave == 0) {
        ull rem0 = 0, rem1 = 0, rem2 = 0, rem3 = 0, rem4 = 0;
        if (nAct > 0) {
            const ull* p = sSup + (size_t)lane * 5;
            ull B0 = p[0], B1 = p[1], B2 = p[2], B3 = p[3], B4 = p[4];
            PIN64(B0); PIN64(B1); PIN64(B2); PIN64(B3); PIN64(B4);
            ull nz = __ballot((B0 | B1 | B2 | B3 | B4) != 0ull);
            while (nz) {
                int i = __builtin_ctzll(nz);
                nz &= nz - 1;
                if (!((rem0 >> i) & 1ull)) {    // uniform: rem identical on all lanes
                    rem0 |= readlane64(B0, i); rem1 |= readlane64(B1, i);
                    rem2 |= readlane64(B2, i); rem3 |= readlane64(B3, i);
                    rem4 |= readlane64(B4, i);
                }
            }
        }
        if (nAct > 64) {
            const ull* p = sSup + (size_t)(64 + lane) * 5;
            ull B0 = p[0], B1 = p[1], B2 = p[2], B3 = p[3], B4 = p[4];
            PIN64(B0); PIN64(B1); PIN64(B2); PIN64(B3); PIN64(B4);
            ull nz = __ballot((B0 | B1 | B2 | B3 | B4) != 0ull);
            while (nz) {
                int i = __builtin_ctzll(nz);
                nz &= nz - 1;
                if (!((rem1 >> i) & 1ull)) {
                    rem0 |= readlane64(B0, i); rem1 |= readlane64(B1, i);
                    rem2 |= readlane64(B2, i); rem3 |= readlane64(B3, i);
                    rem4 |= readlane64(B4, i);
                }
            }
        }
        if (nAct > 128) {
            const ull* p = sSup + (size_t)(128 + lane) * 5;
            ull B0 = p[0], B1 = p[1], B2 = p[2], B3 = p[3], B4 = p[4];
            PIN64(B0); PIN64(B1); PIN64(B2); PIN64(B3); PIN64(B4);
            ull nz = __ballot((B0 | B1 | B2 | B3 | B4) != 0ull);
            while (nz) {
                int i = __builtin_ctzll(nz);
                nz &= nz - 1;
                if (!((rem2 >> i) & 1ull)) {
                    rem0 |= readlane64(B0, i); rem1 |= readlane64(B1, i);
                    rem2 |= readlane64(B2, i); rem3 |= readlane64(B3, i);
                    rem4 |= readlane64(B4, i);
                }
            }
        }
        if (nAct > 192) {
            const ull* p = sSup + (size_t)(192 + lane) * 5;
            ull B0 = p[0], B1 = p[1], B2 = p[2], B3 = p[3], B4 = p[4];
            PIN64(B0); PIN64(B1); PIN64(B2); PIN64(B3); PIN64(B4);
            ull nz = __ballot((B0 | B1 | B2 | B3 | B4) != 0ull);
            while (nz) {
                int i = __builtin_ctzll(nz);
                nz &= nz - 1;
                if (!((rem3 >> i) & 1ull)) {
                    rem0 |= readlane64(B0, i); rem1 |= readlane64(B1, i);
                    rem2 |= readlane64(B2, i); rem3 |= readlane64(B3, i);
                    rem4 |= readlane64(B4, i);
                }
            }
        }
        if (nAct > 256) {
            const bool v4 = lane < (TOPK - 256);
            const ull* p = sSup + (size_t)(256 + (v4 ? lane : 0)) * 5;
            ull B0 = v4 ? p[0] : 0ull, B1 = v4 ? p[1] : 0ull, B2 = v4 ? p[2] : 0ull,
                B3 = v4 ? p[3] : 0ull, B4 = v4 ? p[4] : 0ull;
            PIN64(B0); PIN64(B1); PIN64(B2); PIN64(B3); PIN64(B4);
            ull nz = __ballot((B0 | B1 | B2 | B3 | B4) != 0ull);
            while (nz) {
                int i = __builtin_ctzll(nz);
                nz &= nz - 1;
                if (!((rem4 >> i) & 1ull)) {
                    rem0 |= readlane64(B0, i); rem1 |= readlane64(B1, i);
                    rem2 |= readlane64(B2, i); rem3 |= readlane64(B3, i);
                    rem4 |= readlane64(B4, i);
                }
            }
        }
        if (lane == 0) {
            s_remC[0] = rem0; s_remC[1] = rem1; s_remC[2] = rem2;
            s_remC[3] = rem3; s_remC[4] = rem4;
        }
    }
    __syncthreads();

    // ---- output: thread r writes row r (coalesced 24B/thread). Inactive
    // (zero-area) rows are never suppressed -> kept; active rows look up
    // their compacted suppressed bit. ----
    {
        const int r = tid;
        if (r < TOPK) {
            float x1 = 0.f, y1 = 0.f, x2 = 0.f, y2 = 0.f, vv = 0.f, cc = 0.f;
            if (r < numSel) {
                bool sup = false;
                if (sAr[r] > 0.0f) {
                    int p = (int)sPos[r];
                    sup = (s_remC[p >> 6] >> (p & 63)) & 1ull;
                }
                if (!sup) {
                    float4 bb = sBox[r];
                    x1 = bb.x; y1 = bb.y; x2 = bb.z; y2 = bb.w;
                    vv = sVal[r]; cc = (float)c;
                }
            }
            float* outp = out + ((size_t)b * NC + c) * (TOPK * 6);
            float* row = outp + r * 6;
            *(float2*)(row)     = float2{x1, y1};
            *(float2*)(row + 2) = float2{x2, y2};
            *(float2*)(row + 4) = float2{vv, cc};
        }
    }
}

extern "C" void kernel_launch(void* const* d_in, const int* in_sizes, int n_in,
                              void* d_out, int out_size, void* d_ws, size_t ws_size,
                              hipStream_t stream) {
    const float* in = (const float*)d_in[0];
    float* out = (float*)d_out;
    (void)d_ws; (void)ws_size;   // fused kernel keeps all intermediates in LDS

    k_fused<<<NTASK, NT, 0, stream>>>(in, out);
}

// Round 7
// 83.225 us; speedup vs baseline: 1.0109x; 1.0109x over previous
//
#include <hip/hip_runtime.h>
#include <cstdint>

#pragma clang fp contract(off)

#define NB      32
#define NC      18
#define NA      8400
#define NCH     (4 + NC)
#define NTASK   (NB * NC)      // 576
#define TOPK    300
#define TARGET  316        // fast path needs pcnt >= TOPK; 316 keeps margin
#define NBINS   2048
#define CAP     1024
#define CONF    0.25f
#define IOU_T   0.45f
#define NT      512
#define NW      (NT / 64)
// Prefilter: N(0,1) logits, top-316 cutoff ~1.75 +- 0.1; count(x>1.4) in [553,803] (5-sigma).
// Fast path requires TARGET <= pcnt <= CAP, else exact fallback.
#define PREF_X  1.4f
// sigmoid(x) > 0.25  <=>  x > -ln(3). Outside [XLO,XHI] analytic compare is exact.
#define XHI     (-1.0984f)
#define XLO     (-1.0988f)

// Fast-path binning is on SIGMOID bits (positive floats: raw bits monotone).
// x>1.4 => sv > 0.80218 => bits >= 0x3F4D6049 > SV_KBASE. sv<=1.0 => bin<=1632<NBINS.
#define SV_KBASE 0x3F4D0000u
#define SV_SHIFT 11
// Fallback binning: conf_pass x-mono-keys start ~0x40735C26.
#define FB_KBASE   0x40000000u
#define FB_SHIFT   21

// Exact div-free IoU compare: RN_f32(inter/D) > 0.45f  <=>  inter > M45*D.
// M45 = fp32(0.45) + 2^-26 (25-bit mantissa, exact in f64; x 24-bit D -> exact
// 49-bit product). Tie rounds-to-even back to 0.45f => not >, matching. Bit-exact.
#define M45 (30198989.0 / 67108864.0)

typedef unsigned long long ull;

__device__ __forceinline__ float sigmoidf(float x) {
    return 1.0f / (1.0f + expf(-x));
}
__device__ __forceinline__ unsigned int mono_key(unsigned int bits) {
    return (bits & 0x80000000u) ? ~bits : (bits | 0x80000000u);
}
__device__ __forceinline__ bool conf_pass(float x) {
    if (x >= XHI) return true;
    if (x <= XLO) return false;
    return sigmoidf(x) > CONF;   // rare exact band (~1 element per task)
}
__device__ __forceinline__ unsigned int make_key(float x) {
    return conf_pass(x) ? mono_key(__float_as_uint(x)) : 0u;
}
__device__ __forceinline__ ull readlane64(ull v, int i) {
    unsigned lo = (unsigned)__builtin_amdgcn_readlane((int)(unsigned)(v & 0xFFFFFFFFull), i);
    unsigned hi = (unsigned)__builtin_amdgcn_readlane((int)(unsigned)(v >> 32), i);
    return ((ull)hi << 32) | (ull)lo;
}

// Suffix-find over hist: T1 s.t. count(bins > T1) < target <= count(bins >= T1).
// (fallback path only)
__device__ __forceinline__ void suffix_find(unsigned int* hist, unsigned int* wtot,
                                            int target, int tid, int* s_T1) {
    const int base = tid * (NBINS / NT);
    unsigned int v = 0;
#pragma unroll
    for (int k = 0; k < NBINS / NT; ++k) v += hist[base + k];
    const int lane = tid & 63;
    unsigned int s = v;
#pragma unroll
    for (int d = 1; d < 64; d <<= 1) {
        unsigned int o = __shfl_down(s, d, 64);
        if (lane + d < 64) s += o;
    }
    if (lane == 0) wtot[tid >> 6] = s;
    __syncthreads();
    unsigned int above_waves = 0;
    for (int wv = (tid >> 6) + 1; wv < NW; ++wv) above_waves += wtot[wv];
    unsigned int acc = (s - v) + above_waves;
    for (int bin = base + (NBINS / NT) - 1; bin >= base; --bin) {
        unsigned int cnt = hist[bin];
        if (acc < (unsigned int)target && acc + cnt >= (unsigned int)target) *s_T1 = bin;
        acc += cnt;
    }
    __syncthreads();
}

// Pool layout: [0,8192) hist (suffix-scanned IN PLACE -> S; cand2 in fallback;
// -> sSup) ; [8192,16384) cand (-> sorted). All reuses are barrier-separated.
#define OFF_CAND   8192
#define POOL1_BYTES 16384

// PIN: keep loaded mask words in VGPRs across the serial scan (compiler
// otherwise rematerializes the loads inside the scan loop).
#define PIN64(x) asm volatile("" : "+v"(x))

// ============ Fused: select -> counting-sort rank -> compacted NMS -> output.
// One block per task; all intermediates in LDS.
// (1) Exact counting sort on sigmoid-bit keys; suffix-scan IN PLACE over hist.
// (2) Zero-area rows (~75%) provably have inter==0.0f vs all boxes -> NMS in
//     compacted active space (~75 rows).
// (3) Overlapped epilogue: after the mask barrier, waves 1-7 write all
//     INACTIVE output rows (scan-independent) while wave 0 runs the serial
//     greedy scan and then writes the ~75 active rows itself from in-register
//     rem bits via actIdx. No final barrier, no s_remC/sPos round-trip.
__global__ __launch_bounds__(NT, 4) void k_fused(const float* __restrict__ in,
                                                 float* __restrict__ out) {
    __shared__ __align__(16) unsigned char pool[POOL1_BYTES];
    __shared__ __align__(16) float4 sBox[TOPK];
    __shared__ float sVal[TOPK];
    __shared__ float sAr[TOPK];
    __shared__ unsigned short slotArr[CAP];   // within-bin arrival slot
    __shared__ unsigned int wtot[NW];
    __shared__ unsigned short actIdx[TOPK];   // compacted pos -> row
    __shared__ unsigned int s_cnt, s_cnt2, s_nAct;
    __shared__ int s_T1;

    unsigned int* hist = (unsigned int*)pool;   // -> S (in-place suffix counts)
    ull* cand   = (ull*)(pool + OFF_CAND);
    ull* sorted = (ull*)(pool + OFF_CAND);  // overlays cand, barrier-separated
    ull* cand2  = (ull*)pool;               // fallback only
    ull* sSup   = (ull*)pool;               // valid after rank barrier

    const int tid = threadIdx.x;
    const int lane = tid & 63;
    const int wave = tid >> 6;
    const ull ltm = (1ull << lane) - 1ull;
    const int t = blockIdx.x;
    // XCD swizzle: image b -> XCD b%8 (18 class-tasks of an image share box rows in L2)
    const int b = (t & 7) + 8 * ((t >> 3) & 3);
    const int c = t >> 5;
    const float* cls = in + (size_t)b * NCH * NA + (size_t)(4 + c) * NA;
    const float* box = in + (size_t)b * NCH * NA;
    float* outp = out + ((size_t)b * NC + c) * (TOPK * 6);

    // issue first two P1 loads BEFORE LDS init (latency hides under zeroing)
    const float4* cls4 = (const float4*)cls;
    float4 v  = cls4[tid];              // tid < 512 <= 2100: valid
    float4 vn = cls4[tid + NT];         // tid+512 <= 1023 < 2100: valid

    for (int i = tid; i < NBINS; i += NT) hist[i] = 0;
    if (tid == 0) { s_cnt = 0; s_cnt2 = 0; s_T1 = -1; }
    __syncthreads();

    // P1: prefilter x>1.4, wave-aggregated compaction; sv computed here; sv-bin
    // histogram (atomic return = slot). 2-deep rolling prefetch.
    for (int q = tid; q < NA / 4; q += NT) {
        const int qpp = q + 2 * NT;
        float4 vf;
        const bool havef = qpp < NA / 4;
        if (havef) vf = cls4[qpp];

        const unsigned int i0 = (unsigned int)q * 4u;
        float xs[4] = {v.x, v.y, v.z, v.w};
        ull m[4];
        unsigned int cnt = 0;
#pragma unroll
        for (int u = 0; u < 4; ++u) {
            m[u] = __ballot(xs[u] > PREF_X);
            cnt += (unsigned int)__popcll(m[u]);
        }
        if (cnt) {
            unsigned int base = 0;
            if (lane == 0) base = atomicAdd(&s_cnt, cnt);
            base = (unsigned int)__builtin_amdgcn_readfirstlane((int)base);
            unsigned int pre = 0;
#pragma unroll
            for (int u = 0; u < 4; ++u) {
                if (xs[u] > PREF_X) {
                    float sv = sigmoidf(xs[u]);
                    unsigned int svb = __float_as_uint(sv);
                    unsigned int bin = min((svb - SV_KBASE) >> SV_SHIFT,
                                           (unsigned)(NBINS - 1));
                    unsigned int slot = atomicAdd(&hist[bin], 1u);
                    unsigned int p = base + pre + (unsigned int)__popcll(m[u] & ltm);
                    if (p < CAP) {
                        cand[p] = ((ull)svb << 32) | (ull)(~(i0 + u));
                        slotArr[p] = (unsigned short)slot;
                    }
                }
                pre += (unsigned int)__popcll(m[u]);
            }
        }
        v = vn; vn = vf;
    }
    __syncthreads();

    const int pcnt = (int)s_cnt;
    int numSel;
    if (pcnt >= TARGET && pcnt <= CAP) {
        // ================= fast path: exact counting-sort rank =================
        numSel = TOPK;    // pcnt >= 316 > 300

        // stage A: read my <=2 candidates and ISSUE scattered box gathers NOW --
        // their latency hides under the suffix-scan below. All cand reads
        // complete before the scan's barriers, so the later scatter into
        // sorted (which overlays cand) is race-free.
        ull k0 = 0, k1 = 0;
        unsigned int slot0 = 0, slot1 = 0;
        const bool a0 = tid < pcnt, a1 = tid + NT < pcnt;
        float cx0 = 0.f, cy0 = 0.f, w0 = 0.f, h0 = 0.f;
        float cx1 = 0.f, cy1 = 0.f, w1 = 0.f, h1 = 0.f;
        if (a0) {
            k0 = cand[tid];
            slot0 = (unsigned int)slotArr[tid];
            unsigned int i = ~(unsigned int)(k0 & 0xFFFFFFFFull);
            cx0 = box[i]; cy0 = box[NA + i]; w0 = box[2 * NA + i]; h0 = box[3 * NA + i];
        }
        if (a1) {
            k1 = cand[tid + NT];
            slot1 = (unsigned int)slotArr[tid + NT];
            unsigned int i = ~(unsigned int)(k1 & 0xFFFFFFFFull);
            cx1 = box[i]; cy1 = box[NA + i]; w1 = box[2 * NA + i]; h1 = box[3 * NA + i];
        }

        // in-place suffix-scan: hist[bin] := S[bin] = # keys in bins > bin.
        {
            const int basebin = tid * (NBINS / NT);
            unsigned int cs[NBINS / NT];
            unsigned int vsum = 0;
#pragma unroll
            for (int k = 0; k < NBINS / NT; ++k) { cs[k] = hist[basebin + k]; vsum += cs[k]; }
            unsigned int s = vsum;
#pragma unroll
            for (int d = 1; d < 64; d <<= 1) {
                unsigned int o = __shfl_down(s, d, 64);
                if (lane + d < 64) s += o;
            }
            if (lane == 0) wtot[wave] = s;
            __syncthreads();
            unsigned int above = 0;
            for (int w2 = wave + 1; w2 < NW; ++w2) above += wtot[w2];
            unsigned int acc = (s - vsum) + above;
#pragma unroll
            for (int k = NBINS / NT - 1; k >= 0; --k) { hist[basebin + k] = acc; acc += cs[k]; }
        }
        __syncthreads();

        // compute positions from S (=hist), scatter into sorted
        unsigned int g0 = 0, g1 = 0, c0 = 0, c1 = 0;
        if (a0) {
            unsigned int svb = (unsigned int)(k0 >> 32);
            unsigned int bin = min((svb - SV_KBASE) >> SV_SHIFT, (unsigned)(NBINS - 1));
            g0 = hist[bin];
            c0 = (bin ? hist[bin - 1] : (unsigned int)pcnt) - g0;
            sorted[g0 + slot0] = k0;
        }
        if (a1) {
            unsigned int svb = (unsigned int)(k1 >> 32);
            unsigned int bin = min((svb - SV_KBASE) >> SV_SHIFT, (unsigned)(NBINS - 1));
            g1 = hist[bin];
            c1 = (bin ? hist[bin - 1] : (unsigned int)pcnt) - g1;
            sorted[g1 + slot1] = k1;
        }
        __syncthreads();

        // final rank = S[bin] + #(bin-mates with greater key); gather-write
        if (a0) {
            int rank = (int)g0;
            for (unsigned int j = g0; j < g0 + c0; ++j) rank += (sorted[j] > k0) ? 1 : 0;
            if (rank < TOPK) {
                float hw = w0 * 0.5f, hh = h0 * 0.5f;
                float x1 = cx0 - hw, y1 = cy0 - hh, x2 = cx0 + hw, y2 = cy0 + hh;
                sBox[rank] = float4{x1, y1, x2, y2};
                sVal[rank] = __uint_as_float((unsigned int)(k0 >> 32));
                sAr[rank] = fmaxf(x2 - x1, 0.f) * fmaxf(y2 - y1, 0.f);
            }
        }
        if (a1) {
            int rank = (int)g1;
            for (unsigned int j = g1; j < g1 + c1; ++j) rank += (sorted[j] > k1) ? 1 : 0;
            if (rank < TOPK) {
                float hw = w1 * 0.5f, hh = h1 * 0.5f;
                float x1 = cx1 - hw, y1 = cy1 - hh, x2 = cx1 + hw, y2 = cy1 + hh;
                sBox[rank] = float4{x1, y1, x2, y2};
                sVal[rank] = __uint_as_float((unsigned int)(k1 >> 32));
                sAr[rank] = fmaxf(x2 - x1, 0.f) * fmaxf(y2 - y1, 0.f);
            }
        }
        __syncthreads();      // sorted dead; pool -> sSup
    } else {
        // ---- exact fallback (rare): re-zero hist, full conf_pass histogram,
        // threshold, then O(F^2) rank-by-counting (verbatim from R4). ----
        __syncthreads();
        for (int i = tid; i < NBINS; i += NT) hist[i] = 0;
        __syncthreads();
        {
            for (int q = tid; q < NA / 4; q += NT) {
                float4 vq = cls4[q];
                unsigned int kx = make_key(vq.x), ky = make_key(vq.y);
                unsigned int kz = make_key(vq.z), kw = make_key(vq.w);
                if (kx) atomicAdd(&hist[min((kx - FB_KBASE) >> FB_SHIFT, (unsigned)(NBINS - 1))], 1u);
                if (ky) atomicAdd(&hist[min((ky - FB_KBASE) >> FB_SHIFT, (unsigned)(NBINS - 1))], 1u);
                if (kz) atomicAdd(&hist[min((kz - FB_KBASE) >> FB_SHIFT, (unsigned)(NBINS - 1))], 1u);
                if (kw) atomicAdd(&hist[min((kw - FB_KBASE) >> FB_SHIFT, (unsigned)(NBINS - 1))], 1u);
            }
        }
        __syncthreads();
        suffix_find(hist, wtot, TARGET, tid, &s_T1);
        {
            const ull thr = (s_T1 < 0) ? 0ull
                : ((ull)FB_KBASE + ((ull)(unsigned int)s_T1 << FB_SHIFT));
            for (int q = tid; q < NA / 4; q += NT) {
                float4 vq = cls4[q];
                const unsigned int i0 = (unsigned int)q * 4u;
                float xs[4] = {vq.x, vq.y, vq.z, vq.w};
#pragma unroll
                for (int u = 0; u < 4; ++u) {
                    unsigned int d = make_key(xs[u]);
                    if (d && (ull)d >= thr) {
                        unsigned int p = atomicAdd(&s_cnt2, 1u);
                        if (p < CAP) {
                            float sv = sigmoidf(xs[u]);
                            cand2[p] = ((ull)__float_as_uint(sv) << 32) | (ull)(~(i0 + u));
                        }
                    }
                }
            }
        }
        __syncthreads();
        const int F = min((int)s_cnt2, CAP);
        numSel = min(F, TOPK);
        for (int e = tid; e < F; e += NT) {
            ull k = cand2[e];
            unsigned int i = ~(unsigned int)(k & 0xFFFFFFFFull);
            float cx = box[i];
            float cy = box[NA + i];
            float w  = box[2 * NA + i];
            float h  = box[3 * NA + i];
            int rank = 0;
            int o = 0;
#pragma unroll 2
            for (; o + 4 <= F; o += 4) {
                ulonglong2 p0 = *(const ulonglong2*)&cand2[o];
                ulonglong2 p1 = *(const ulonglong2*)&cand2[o + 2];
                rank += (p0.x > k) + (p0.y > k) + (p1.x > k) + (p1.y > k);
            }
            for (; o < F; ++o) rank += (cand2[o] > k) ? 1 : 0;
            if (rank < TOPK) {
                float hw = w * 0.5f, hh = h * 0.5f;
                float x1 = cx - hw, y1 = cy - hh, x2 = cx + hw, y2 = cy + hh;
                sBox[rank] = float4{x1, y1, x2, y2};
                sVal[rank] = __uint_as_float((unsigned int)(k >> 32));
                sAr[rank] = fmaxf(x2 - x1, 0.f) * fmaxf(y2 - y1, 0.f);
            }
        }
        __syncthreads();      // cand2 dead; pool -> sSup
    }

    // ---- order-preserving compaction of active rows ----
    {
        int r = tid;
        bool act = (r < TOPK) && (r < numSel) && (sAr[r] > 0.0f);
        ull mb = __ballot(act);
        if (lane == 0) wtot[wave] = (unsigned int)__popcll(mb);
        __syncthreads();
        unsigned int basew = 0;
        for (int w2 = 0; w2 < wave; ++w2) basew += wtot[w2];
        if (tid == 0) {
            unsigned int tot = 0;
            for (int w2 = 0; w2 < NW; ++w2) tot += wtot[w2];
            s_nAct = tot;
        }
        if (act) {
            unsigned int p = basew + (unsigned int)__popcll(mb & ltm);
            actIdx[p] = (unsigned short)r;
        }
    }
    __syncthreads();
    const int nAct = (int)s_nAct;

    // ---- suppression-mask build in COMPACTED space: every active row writes
    // all 5 words (0 outside [w0,wlast]); tail rows [nAct, ceil64(nAct)) zeroed
    // in the same phase (disjoint addresses -> no barrier needed between). ----
    {
        float4 cb[5];
        float ca[5];
#pragma unroll
        for (int w = 0; w < 5; ++w) {
            int jc = (w << 6) + lane;
            bool vv = jc < nAct;
            int j = vv ? (int)actIdx[jc] : 0;
            cb[w] = vv ? sBox[j] : float4{0.f, 0.f, 0.f, 0.f};
            ca[w] = vv ? sAr[j] : 0.f;
        }
        const int wlast = (nAct > 0) ? ((nAct - 1) >> 6) : -1;
        for (int p = wave; p < nAct; p += NW) {
            int r = actIdx[p];
            float4 bi = sBox[r];
            float ai = sAr[r];
            const int w0 = p >> 6;
#pragma unroll
            for (int w = 0; w < 5; ++w) {
                ull bal = 0ull;
                if (w >= w0 && w <= wlast) {   // uniform branch
                    const int jc = (w << 6) + lane;
                    bool supb = false;
                    if (jc < nAct && jc > p) {
                        float xx1 = fmaxf(bi.x, cb[w].x);
                        float yy1 = fmaxf(bi.y, cb[w].y);
                        float xx2 = fminf(bi.z, cb[w].z);
                        float yy2 = fminf(bi.w, cb[w].w);
                        float iw = fmaxf(xx2 - xx1, 0.0f);
                        float ih = fmaxf(yy2 - yy1, 0.0f);
                        float inter = iw * ih;
                        float un = ai + ca[w] - inter;
                        float D = fmaxf(un, 1e-9f);
                        supb = (double)inter > M45 * (double)D;  // == RN(inter/D) > 0.45f
                    }
                    bal = __ballot(supb);
                }
                if (lane == 0) sSup[p * 5 + w] = bal;
            }
        }
        // tail zero: rows [nAct, ceil64(nAct)) so scan's full 64-lane group
        // reads see zeros past nAct. Rows >= ceil64 are never read.
        const int zend = min((nAct + 63) & ~63, TOPK);
        for (int i = nAct * 5 + tid; i < zend * 5; i += NT) sSup[i] = 0ull;
    }
    __syncthreads();

    // ---- overlapped epilogue: waves 1-7 write scan-independent rows NOW;
    // wave 0 runs the greedy scan then writes the active rows itself. ----
    if (wave != 0) {
        // rows 0..299 covered once by tid in [64, 364)
        const int r = tid - 64;
        if (r < TOPK) {
            const bool active = (r < numSel) && (sAr[r] > 0.0f);
            if (!active) {
                float x1 = 0.f, y1 = 0.f, x2 = 0.f, y2 = 0.f, vv = 0.f, cc = 0.f;
                if (r < numSel) {          // inactive kept row
                    float4 bb = sBox[r];
                    x1 = bb.x; y1 = bb.y; x2 = bb.z; y2 = bb.w;
                    vv = sVal[r]; cc = (float)c;
                }
                float* row = outp + r * 6;
                *(float2*)(row)     = float2{x1, y1};
                *(float2*)(row + 2) = float2{x2, y2};
                *(float2*)(row + 4) = float2{vv, cc};
            }
        }
        return;
    }

    // wave 0: greedy scan over compacted rows (nz-skip over zero rows)
    ull rem0 = 0, rem1 = 0, rem2 = 0, rem3 = 0, rem4 = 0;
    if (nAct > 0) {
        const ull* p = sSup + (size_t)lane * 5;
        ull B0 = p[0], B1 = p[1], B2 = p[2], B3 = p[3], B4 = p[4];
        PIN64(B0); PIN64(B1); PIN64(B2); PIN64(B3); PIN64(B4);
        ull nz = __ballot((B0 | B1 | B2 | B3 | B4) != 0ull);
        while (nz) {
            int i = __builtin_ctzll(nz);
            nz &= nz - 1;
            if (!((rem0 >> i) & 1ull)) {    // uniform: rem identical on all lanes
                rem0 |= readlane64(B0, i); rem1 |= readlane64(B1, i);
                rem2 |= readlane64(B2, i); rem3 |= readlane64(B3, i);
                rem4 |= readlane64(B4, i);
            }
        }
    }
    if (nAct > 64) {
        const ull* p = sSup + (size_t)(64 + lane) * 5;
        ull B0 = p[0], B1 = p[1], B2 = p[2], B3 = p[3], B4 = p[4];
        PIN64(B0); PIN64(B1); PIN64(B2); PIN64(B3); PIN64(B4);
        ull nz = __ballot((B0 | B1 | B2 | B3 | B4) != 0ull);
        while (nz) {
            int i = __builtin_ctzll(nz);
            nz &= nz - 1;
            if (!((rem1 >> i) & 1ull)) {
                rem0 |= readlane64(B0, i); rem1 |= readlane64(B1, i);
                rem2 |= readlane64(B2, i); rem3 |= readlane64(B3, i);
                rem4 |= readlane64(B4, i);
            }
        }
    }
    if (nAct > 128) {
        const ull* p = sSup + (size_t)(128 + lane) * 5;
        ull B0 = p[0], B1 = p[1], B2 = p[2], B3 = p[3], B4 = p[4];
        PIN64(B0); PIN64(B1); PIN64(B2); PIN64(B3); PIN64(B4);
        ull nz = __ballot((B0 | B1 | B2 | B3 | B4) != 0ull);
        while (nz) {
            int i = __builtin_ctzll(nz);
            nz &= nz - 1;
            if (!((rem2 >> i) & 1ull)) {
                rem0 |= readlane64(B0, i); rem1 |= readlane64(B1, i);
                rem2 |= readlane64(B2, i); rem3 |= readlane64(B3, i);
                rem4 |= readlane64(B4, i);
            }
        }
    }
    if (nAct > 192) {
        const ull* p = sSup + (size_t)(192 + lane) * 5;
        ull B0 = p[0], B1 = p[1], B2 = p[2], B3 = p[3], B4 = p[4];
        PIN64(B0); PIN64(B1); PIN64(B2); PIN64(B3); PIN64(B4);
        ull nz = __ballot((B0 | B1 | B2 | B3 | B4) != 0ull);
        while (nz) {
            int i = __builtin_ctzll(nz);
            nz &= nz - 1;
            if (!((rem3 >> i) & 1ull)) {
                rem0 |= readlane64(B0, i); rem1 |= readlane64(B1, i);
                rem2 |= readlane64(B2, i); rem3 |= readlane64(B3, i);
                rem4 |= readlane64(B4, i);
            }
        }
    }
    if (nAct > 256) {
        const bool v4 = lane < (TOPK - 256);
        const ull* p = sSup + (size_t)(256 + (v4 ? lane : 0)) * 5;
        ull B0 = v4 ? p[0] : 0ull, B1 = v4 ? p[1] : 0ull, B2 = v4 ? p[2] : 0ull,
            B3 = v4 ? p[3] : 0ull, B4 = v4 ? p[4] : 0ull;
        PIN64(B0); PIN64(B1); PIN64(B2); PIN64(B3); PIN64(B4);
        ull nz = __ballot((B0 | B1 | B2 | B3 | B4) != 0ull);
        while (nz) {
            int i = __builtin_ctzll(nz);
            nz &= nz - 1;
            if (!((rem4 >> i) & 1ull)) {
                rem0 |= readlane64(B0, i); rem1 |= readlane64(B1, i);
                rem2 |= readlane64(B2, i); rem3 |= readlane64(B3, i);
                rem4 |= readlane64(B4, i);
            }
        }
    }

    // wave 0 writes the active rows from in-register rem bits
    {
        ull remw[5] = {rem0, rem1, rem2, rem3, rem4};
#pragma unroll
        for (int g = 0; g < 5; ++g) {
            const int p = (g << 6) + lane;
            if (p < nAct) {
                const int r = (int)actIdx[p];
                float x1 = 0.f, y1 = 0.f, x2 = 0.f, y2 = 0.f, vv = 0.f, cc = 0.f;
                if (!((remw[g] >> lane) & 1ull)) {
                    float4 bb = sBox[r];
                    x1 = bb.x; y1 = bb.y; x2 = bb.z; y2 = bb.w;
                    vv = sVal[r]; cc = (float)c;
                }
                float* row = outp + r * 6;
                *(float2*)(row)     = float2{x1, y1};
                *(float2*)(row + 2) = float2{x2, y2};
                *(float2*)(row + 4) = float2{vv, cc};
            }
        }
    }
}

extern "C" void kernel_launch(void* const* d_in, const int* in_sizes, int n_in,
                              void* d_out, int out_size, void* d_ws, size_t ws_size,
                              hipStream_t stream) {
    const float* in = (const float*)d_in[0];
    float* out = (float*)d_out;
    (void)d_ws; (void)ws_size;   // fused kernel keeps all intermediates in LDS

    k_fused<<<NTASK, NT, 0, stream>>>(in, out);
}